// Round 2
// baseline (119.162 us; speedup 1.0000x reference)
//
#include <hip/hip_runtime.h>
#include <stdint.h>

typedef unsigned long long u64;

static constexpr int T = 1024;
static constexpr int B = 2;
static constexpr int N = 10000;
static constexpr int L = 30;
static constexpr int S = 2 * L + 1;   // 61

static constexpr int NBLK  = 2048;    // all blocks sweep; blocks 0..255 also do corr
static constexpr int CHUNK = 2500;    // float4 per block; 2048*2500 == 5,120,000 == T*B*N/4
static constexpr int TAIL  = CHUNK - 9 * 256;   // 196

static constexpr u64 ALL   = (1ULL << S) - 1;
static constexpr u64 EVENM = 0x5555555555555555ULL & ((1ULL << S) - 1);

__device__ __forceinline__ float block_reduce(float s) {
    for (int off = 32; off; off >>= 1) s += __shfl_down(s, off, 64);
    __shared__ float tmp[8];
    int lane = threadIdx.x & 63, w = threadIdx.x >> 6;
    int nw = blockDim.x >> 6;
    if (lane == 0) tmp[w] = s;
    __syncthreads();
    float t = 0.f;
    if (threadIdx.x == 0)
        for (int i = 0; i < nw; ++i) t += tmp[i];
    return t;
}

__device__ __forceinline__ float sq4(float4 v) {
    return v.x * v.x + v.y * v.y + v.z * v.z + v.w * v.w;
}

// All 2048 blocks sweep one contiguous 2500-float4 chunk (perfect balance, no
// boundary predication except the 196-thread tail). Blocks 0..255 additionally
// compute the CTC-lattice masked correction FIRST (1 scattered load/thread,
// overlapped with the streaming sweep). Partials per block; no same-address
// atomics (round-2 lesson).
__global__ void k_fused(const float4* __restrict__ x4, const float* __restrict__ x,
                        const int* __restrict__ label, float* __restrict__ partials) {
    float s = 0.f;
    int tid = threadIdx.x;

    if (blockIdx.x < 256) {
        __shared__ int labs[B][L];
        __shared__ u64 dups[B][L];
        __shared__ u64 AfS[B], AbS[B];
        if (tid < B) {
            int b = tid;
            int lb[L];
            u64 Af = 0, Ab = 0;
            #pragma unroll
            for (int k = 0; k < L; ++k) { lb[k] = label[b * L + k]; labs[b][k] = lb[k]; }
            #pragma unroll
            for (int k = 0; k < L; ++k) {
                u64 bit = 1ULL << (2 * k + 1);
                if (k == 0     || lb[k] != lb[k - 1]) Af |= bit;
                if (k == L - 1 || lb[k] != lb[k + 1]) Ab |= bit;
                u64 d = 0;
                for (int k2 = 0; k2 < k; ++k2)
                    if (lb[k2] == lb[k]) d |= 1ULL << (2 * k2 + 1);
                dups[b][k] = d;
            }
            AfS[b] = Af; AbS[b] = Ab;
        }
        __syncthreads();
        int pair = blockIdx.x * 8 + (tid >> 5);   // 0..2047 == b*T + t
        int lane = tid & 31;
        int b = pair >> 10;
        int t = pair & (T - 1);
        u64 m;
        if (t < 64) {
            // backward map saturated (t <= T-61); forward needs t steps
            u64 Af = AfS[b];
            u64 c = 3ULL;
            for (int i = 0; i < t; ++i) c = (c | (c << 1) | ((c << 2) & Af)) & ALL;
            m = c;
        } else if (t >= T - 64) {
            // forward map saturated (t >= 60); backward needs T-1-t steps
            u64 Ab = AbS[b];
            u64 c = (1ULL << (S - 1)) | (1ULL << (S - 2));
            int n = T - 1 - t;
            for (int i = 0; i < n; ++i) c = c | (c >> 1) | ((c >> 2) & Ab);
            m = c;
        } else {
            m = ALL;
        }
        const float* row = x + (size_t)t * (B * N) + (size_t)b * N;
        if (lane < L) {
            u64 bit = 1ULL << (2 * lane + 1);
            if ((m & bit) && !(m & dups[b][lane])) {
                float v = row[labs[b][lane]];
                s -= v * v;
            }
        } else if (lane == L) {
            if (m & EVENM) { float v = row[0]; s -= v * v; }  // blank, counted once
        }
    }

    // Sweep: contiguous chunk, 9 full rounds + 196-thread tail; two 5-deep
    // independent load batches (MLP 5, VGPR-friendly).
    const float4* p = x4 + (size_t)blockIdx.x * CHUNK + tid;
    float4 v[5];
    #pragma unroll
    for (int j = 0; j < 5; ++j) v[j] = p[j * 256];
    #pragma unroll
    for (int j = 0; j < 5; ++j) s += sq4(v[j]);
    #pragma unroll
    for (int j = 0; j < 4; ++j) v[j] = p[(5 + j) * 256];
    v[4] = (tid < TAIL) ? p[9 * 256] : make_float4(0.f, 0.f, 0.f, 0.f);
    #pragma unroll
    for (int j = 0; j < 5; ++j) s += sq4(v[j]);

    float tot = block_reduce(s);
    if (threadIdx.x == 0) partials[blockIdx.x] = tot;
}

// out = 0.5 * sum(partials)
__global__ void k_final(const float* __restrict__ partials, float* __restrict__ out) {
    float s = 0.f;
    for (int i = threadIdx.x; i < NBLK; i += 256) s += partials[i];
    float tot = block_reduce(s);
    if (threadIdx.x == 0) out[0] = 0.5f * tot;
}

extern "C" void kernel_launch(void* const* d_in, const int* in_sizes, int n_in,
                              void* d_out, int out_size, void* d_ws, size_t ws_size,
                              hipStream_t stream) {
    const float* logits = (const float*)d_in[0];
    const int*   label  = (const int*)d_in[2];
    float* partials = (float*)d_ws;

    k_fused<<<NBLK, 256, 0, stream>>>((const float4*)logits, logits, label, partials);
    k_final<<<1, 256, 0, stream>>>(partials, (float*)d_out);
}